// Round 16
// baseline (213.047 us; speedup 1.0000x reference)
//
#include <hip/hip_runtime.h>
#include <math.h>

#define TPB 256
#define NW (TPB / 64)
#define CAP 256
#define KTOP 10
#define TCAND 11.0f
#define NBLK 2048

typedef float floatx4 __attribute__((ext_vector_type(4)));
typedef unsigned long long u64;
typedef unsigned int u32;

__device__ inline float wredMin(float v) {
#pragma unroll
  for (int o = 32; o >= 1; o >>= 1) v = fminf(v, __shfl_xor(v, o));
  return v;
}
__device__ inline float wredSum(float v) {
#pragma unroll
  for (int o = 32; o >= 1; o >>= 1) v += __shfl_xor(v, o);
  return v;
}
__device__ inline u64 shfl_xor_u64(u64 k, int o) {
  int lo = __shfl_xor((int)(u32)k, o);
  int hi = __shfl_xor((int)(u32)(k >> 32), o);
  return ((u64)(u32)hi << 32) | (u32)lo;
}
__device__ inline u64 wredMaxU64(u64 k) {
#pragma unroll
  for (int o = 32; o >= 1; o >>= 1) {
    u64 ok = shfl_xor_u64(k, o);
    if (ok > k) k = ok;
  }
  return k;
}
// key order == (value desc, index asc): monotone float->u32 in high word, ~idx low.
// 0 is a safe "absent" sentinel (no logit > TCAND maps to 0).
__device__ inline u64 mkkey(float z, int idx) {
  u32 b = __float_as_uint(z);
  u32 u = (b & 0x80000000u) ? ~b : (b | 0x80000000u);
  return ((u64)u << 32) | (u32)~(u32)idx;
}
__device__ inline int keyidx(u64 k) { return (int)~(u32)k; }
__device__ inline float keyval(u64 k) {
  u32 u = (u32)(k >> 32);
  u32 b = (u & 0x80000000u) ? (u ^ 0x80000000u) : ~u;
  return __uint_as_float(b);
}

struct SM {
  u64 pool[CAP];
  u64 warr[NW];
  u64 selArr[KTOP];
  float rmn[NW], rsm[NW];
  int cnt;
  float zy;
  float c_prest, c_ptrue;
  float pk[KTOP];
  int ki[KTOP];
};

__global__ __launch_bounds__(TPB) void fused(
    const float* __restrict__ zg, const int* __restrict__ yv,
    float* __restrict__ out, int B, int C) {
  __shared__ SM S;
  const int tid = threadIdx.x, wid = tid >> 6, lane = tid & 63;
  const int C4 = C >> 2;
  const int Keff = KTOP < (C - 1) ? KTOP : (C - 1);
  const int myrow0 = blockIdx.x;
  const int NB = gridDim.x;
  if (myrow0 >= B) return;
  const int nrows = (B - myrow0 + NB - 1) / NB;

  // write-state (constants of previous row) in registers
  float p_rest = 0.0f, p_true = 0.0f;
  float pk[KTOP];
  int ki[KTOP], sv[KTOP];
  int y_w = 0, svy = -2;
#pragma unroll
  for (int k = 0; k < KTOP; ++k) { pk[k] = 0; ki[k] = -1; sv[k] = -1; }

  // Iteration i: READ row (myrow0 + i*NB), WRITE row (myrow0 + (i-1)*NB).
  for (int it = 0; it <= nrows; ++it) {
    const bool doR = (it < nrows);
    const bool doW = (it >= 1);
    const int rrow = myrow0 + it * NB;
    const int wrow = myrow0 + (it - 1) * NB;
    const float* zr = zg + (size_t)rrow * C;     // deref'd only if doR
    const floatx4* zr4 = (const floatx4*)zr;
    float* orow = out + (size_t)wrow * C;        // deref'd only if doW
    floatx4* out4 = (floatx4*)orow;

    __syncthreads();   // prev selection results stable; pool free for reuse
    if (doW) {
      p_rest = S.c_prest; p_true = S.c_ptrue;
#pragma unroll
      for (int k = 0; k < KTOP; ++k) { pk[k] = S.pk[k]; ki[k] = S.ki[k]; sv[k] = ki[k] >> 2; }
      y_w = yv[wrow]; svy = y_w >> 2;
    }
    int y_r = 0;
    if (doR) y_r = yv[rrow];
    if (doR && tid == 0) { S.cnt = 0; S.zy = zr[y_r]; }
    __syncthreads();

    // ---- Interleaved stream: fill-write row (it-1) + read/reduce row (it) ----
    float lmin = INFINITY, lsum = 0.0f;
    const floatx4 fillv = {p_rest, p_rest, p_rest, p_rest};
    for (int base = 0; base < C4; base += 4 * TPB) {
      const int q0 = base + tid, q1 = q0 + TPB, q2 = q1 + TPB, q3 = q2 + TPB;
      floatx4 x0 = {0, 0, 0, 0}, x1 = {0, 0, 0, 0}, x2 = {0, 0, 0, 0}, x3 = {0, 0, 0, 0};
      bool h0 = false, h1 = false, h2 = false, h3 = false;
      if (doR) {
        h0 = q0 < C4; h1 = q1 < C4; h2 = q2 < C4; h3 = q3 < C4;
        if (h0) x0 = __builtin_nontemporal_load(zr4 + q0);
        if (h1) x1 = __builtin_nontemporal_load(zr4 + q1);
        if (h2) x2 = __builtin_nontemporal_load(zr4 + q2);
        if (h3) x3 = __builtin_nontemporal_load(zr4 + q3);
      }
      if (doW) {
#pragma unroll
        for (int u = 0; u < 4; ++u) {
          int g = base + tid + u * TPB;
          if (g < C4) {
            floatx4 o = fillv;
            bool sp = (g == svy);
#pragma unroll
            for (int k = 0; k < KTOP; ++k) sp |= (g == sv[k]);
            if (sp) {
              int j = g << 2;
#pragma unroll
              for (int l = 0; l < 4; ++l) {
                float p = p_rest;
#pragma unroll
                for (int k = 0; k < KTOP; ++k)
                  if (j + l == ki[k]) p = pk[k];
                if (j + l == y_w) p = p_true;
                o[l] = p;
              }
            }
            __builtin_nontemporal_store(o, &out4[g]);
          }
        }
      }
#define PROC(X, H, Q)                                                                        \
      if (H) {                                                                               \
        lmin = fminf(lmin, fminf(fminf(X.x, X.y), fminf(X.z, X.w)));                         \
        lsum += __expf(X.x) + __expf(X.y) + __expf(X.z) + __expf(X.w);                       \
        if (fmaxf(fmaxf(X.x, X.y), fmaxf(X.z, X.w)) > TCAND) {                               \
          int j = (Q) << 2;                                                                  \
          if (X.x > TCAND && j + 0 != y_r) { int p = atomicAdd(&S.cnt, 1); if (p < CAP) S.pool[p] = mkkey(X.x, j); }     \
          if (X.y > TCAND && j + 1 != y_r) { int p = atomicAdd(&S.cnt, 1); if (p < CAP) S.pool[p] = mkkey(X.y, j + 1); } \
          if (X.z > TCAND && j + 2 != y_r) { int p = atomicAdd(&S.cnt, 1); if (p < CAP) S.pool[p] = mkkey(X.z, j + 2); } \
          if (X.w > TCAND && j + 3 != y_r) { int p = atomicAdd(&S.cnt, 1); if (p < CAP) S.pool[p] = mkkey(X.w, j + 3); } \
        }                                                                                    \
      }
      PROC(x0, h0, q0) PROC(x1, h1, q1) PROC(x2, h2, q2) PROC(x3, h3, q3)
#undef PROC
    }
    // scalar tails (C % 4 != 0 only)
    if (doR) {
      for (int j = (C4 << 2) + tid; j < C; j += TPB) {
        float z = zr[j];
        lmin = fminf(lmin, z);
        lsum += __expf(z);
        if (z > TCAND && j != y_r) { int p = atomicAdd(&S.cnt, 1); if (p < CAP) S.pool[p] = mkkey(z, j); }
      }
    }
    if (doW) {
      for (int j = (C4 << 2) + tid; j < C; j += TPB) {
        float p = p_rest;
#pragma unroll
        for (int k = 0; k < KTOP; ++k)
          if (j == ki[k]) p = pk[k];
        if (j == y_w) p = p_true;
        __builtin_nontemporal_store(p, &orow[j]);
      }
    }

    // ---- Selection + constants for the row just read ----
    if (doR) {
      lmin = wredMin(lmin);
      lsum = wredSum(lsum);
      if (lane == 0) { S.rmn[wid] = lmin; S.rsm[wid] = lsum; }
      __syncthreads();
      const int pc = S.cnt;   // block-uniform
      float vmin = INFINITY, total = 0.0f;
#pragma unroll
      for (int w = 0; w < NW; ++w) { vmin = fminf(vmin, S.rmn[w]); total += S.rsm[w]; }
      const bool ok = (pc >= Keff && pc <= CAP);  // block-uniform

      if (ok) {
        if (wid == 0) {  // barrier-free wave-0 selection, pool in registers
          u64 s0 = (lane < pc)       ? S.pool[lane]       : 0;
          u64 s1 = (lane + 64 < pc)  ? S.pool[lane + 64]  : 0;
          u64 s2 = (lane + 128 < pc) ? S.pool[lane + 128] : 0;
          u64 s3 = (lane + 192 < pc) ? S.pool[lane + 192] : 0;
          u64 sel[KTOP];
          u64 prev = ~0ull;
#pragma unroll
          for (int r = 0; r < KTOP; ++r) {
            u64 loc = 0;
            if (r < Keff) {
              if (s0 < prev && s0 > loc) loc = s0;
              if (s1 < prev && s1 > loc) loc = s1;
              if (s2 < prev && s2 > loc) loc = s2;
              if (s3 < prev && s3 > loc) loc = s3;
            }
            u64 best = wredMaxU64(loc);
            sel[r] = best;
            prev = best;
          }
          if (lane == 0) {
            float Stop = 0.0f;
#pragma unroll
            for (int r = 0; r < KTOP; ++r)
              if (sel[r] != 0) Stop += __expf(keyval(sel[r]));
            const float Sall = total - __expf(S.zy);
            const float ev   = __expf(vmin);
            const float invZ = 1.0f / (Sall + ev);
            float Srest = Sall - Stop;
            if (Srest < 0.0f) Srest = 0.0f;
            float MR = (float)(C - 1 - Keff);
            if (MR < 1.0f) MR = 1.0f;
            S.c_prest = (Srest / MR) * invZ;
            S.c_ptrue = ev * invZ;
#pragma unroll
            for (int r = 0; r < KTOP; ++r) {
              bool have = (sel[r] != 0);
              S.pk[r] = have ? __expf(keyval(sel[r])) * invZ : 0.0f;
              S.ki[r] = have ? keyidx(sel[r]) : -1;
            }
          }
        }
      } else {
        // Exact fallback (pathological): block-wide prev-bounded u64 max rounds.
        u64 prev = ~0ull;
        for (int r = 0; r < KTOP; ++r) {
          u64 loc = 0;
          if (r < Keff) {
            for (int j = tid; j < C; j += TPB) {
              if (j == y_r) continue;
              u64 k = mkkey(zr[j], j);
              if (k < prev && k > loc) loc = k;
            }
          }
          u64 best = wredMaxU64(loc);
          if (lane == 0) S.warr[wid] = best;
          __syncthreads();
          if (tid == 0) {
            u64 b = 0;
#pragma unroll
            for (int w = 0; w < NW; ++w) b = (S.warr[w] > b) ? S.warr[w] : b;
            S.selArr[r] = b;
          }
          __syncthreads();
          prev = S.selArr[r];
        }
        if (tid == 0) {
          float Stop = 0.0f;
#pragma unroll
          for (int r = 0; r < KTOP; ++r)
            if (S.selArr[r] != 0) Stop += __expf(keyval(S.selArr[r]));
          const float Sall = total - __expf(S.zy);
          const float ev   = __expf(vmin);
          const float invZ = 1.0f / (Sall + ev);
          float Srest = Sall - Stop;
          if (Srest < 0.0f) Srest = 0.0f;
          float MR = (float)(C - 1 - Keff);
          if (MR < 1.0f) MR = 1.0f;
          S.c_prest = (Srest / MR) * invZ;
          S.c_ptrue = ev * invZ;
#pragma unroll
          for (int r = 0; r < KTOP; ++r) {
            bool have = (S.selArr[r] != 0);
            S.pk[r] = have ? __expf(keyval(S.selArr[r])) * invZ : 0.0f;
            S.ki[r] = have ? keyidx(S.selArr[r]) : -1;
          }
        }
      }
    }
    // loop-top __syncthreads() of next iteration orders selection -> constant loads
  }
}

extern "C" void kernel_launch(void* const* d_in, const int* in_sizes, int n_in,
                              void* d_out, int out_size, void* d_ws, size_t ws_size,
                              hipStream_t stream) {
  const float* zg = (const float*)d_in[0];
  const int* y    = (const int*)d_in[1];
  float* out      = (float*)d_out;
  const int B = in_sizes[1];
  const int C = in_sizes[0] / B;

  int nb = NBLK < B ? NBLK : B;
  fused<<<nb, TPB, 0, stream>>>(zg, y, out, B, C);
}

// Round 17
// 201.460 us; speedup vs baseline: 1.0575x; 1.0575x over previous
//
#include <hip/hip_runtime.h>
#include <math.h>

#define TPB 256
#define NW (TPB / 64)
#define CAP 256
#define KTOP 10
#define TCAND 11.0f

typedef float floatx4 __attribute__((ext_vector_type(4)));
typedef unsigned long long u64;
typedef unsigned int u32;

__device__ inline float wredMin(float v) {
#pragma unroll
  for (int o = 32; o >= 1; o >>= 1) v = fminf(v, __shfl_xor(v, o));
  return v;
}
__device__ inline float wredSum(float v) {
#pragma unroll
  for (int o = 32; o >= 1; o >>= 1) v += __shfl_xor(v, o);
  return v;
}
__device__ inline u64 shfl_xor_u64(u64 k, int o) {
  int lo = __shfl_xor((int)(u32)k, o);
  int hi = __shfl_xor((int)(u32)(k >> 32), o);
  return ((u64)(u32)hi << 32) | (u32)lo;
}
__device__ inline u64 wredMaxU64(u64 k) {
#pragma unroll
  for (int o = 32; o >= 1; o >>= 1) {
    u64 ok = shfl_xor_u64(k, o);
    if (ok > k) k = ok;
  }
  return k;
}
// key order == (value desc, index asc): monotone float->u32 in high word, ~idx low.
// 0 is a safe "absent" sentinel (no positive logit maps to 0).
__device__ inline u64 mkkey(float z, int idx) {
  u32 b = __float_as_uint(z);
  u32 u = (b & 0x80000000u) ? ~b : (b | 0x80000000u);
  return ((u64)u << 32) | (u32)~(u32)idx;
}
__device__ inline int keyidx(u64 k) { return (int)~(u32)k; }
__device__ inline float keyval(u64 k) {
  u32 u = (u32)(k >> 32);
  u32 b = (u & 0x80000000u) ? (u ^ 0x80000000u) : ~u;
  return __uint_as_float(b);
}

struct SM {
  u64 pool[CAP];
  u64 warr[NW];          // block u64-max staging (fallback)
  u64 selArr[KTOP];      // fallback-selected keys
  float rmn[NW], rsm[NW];
  int cnt;
  float c_prest, c_ptrue;
  float pk[KTOP];
  int ki[KTOP];
};

__global__ __launch_bounds__(TPB) void fused(
    const float* __restrict__ zg, const int* __restrict__ yv,
    float* __restrict__ out, int B, int C) {
  __shared__ SM S;

  const int tid = threadIdx.x, wid = tid >> 6, lane = tid & 63;
  const int row = blockIdx.x;
  const float* zr = zg + (size_t)row * C;
  const floatx4* zr4 = (const floatx4*)zr;
  const int C4 = C >> 2;
  const int y = yv[row];
  const int Keff = KTOP < (C - 1) ? KTOP : (C - 1);

  float zy0 = 0.0f;
  if (tid == 0) { S.cnt = 0; zy0 = zr[y]; }
  __syncthreads();

  // ---- Phase 1: single streamed read. min(all), sum exp(all); candidates
  // > TCAND (y excluded) -> LDS pool as u64 keys. No re-reads, no retries.
  float lmin = INFINITY, lsum = 0.0f;
  for (int base = 0; base < C4; base += 4 * TPB) {
    const int q0 = base + tid, q1 = q0 + TPB, q2 = q1 + TPB, q3 = q2 + TPB;
    const bool h0 = q0 < C4, h1 = q1 < C4, h2 = q2 < C4, h3 = q3 < C4;
    floatx4 x0 = {0, 0, 0, 0}, x1 = {0, 0, 0, 0}, x2 = {0, 0, 0, 0}, x3 = {0, 0, 0, 0};
    if (h0) x0 = __builtin_nontemporal_load(zr4 + q0);
    if (h1) x1 = __builtin_nontemporal_load(zr4 + q1);
    if (h2) x2 = __builtin_nontemporal_load(zr4 + q2);
    if (h3) x3 = __builtin_nontemporal_load(zr4 + q3);
#define PROC(X, H, Q)                                                                        \
    if (H) {                                                                                 \
      lmin = fminf(lmin, fminf(fminf(X.x, X.y), fminf(X.z, X.w)));                           \
      lsum += __expf(X.x) + __expf(X.y) + __expf(X.z) + __expf(X.w);                         \
      if (fmaxf(fmaxf(X.x, X.y), fmaxf(X.z, X.w)) > TCAND) {                                 \
        int j = (Q) << 2;                                                                    \
        if (X.x > TCAND && j + 0 != y) { int p = atomicAdd(&S.cnt, 1); if (p < CAP) S.pool[p] = mkkey(X.x, j); }     \
        if (X.y > TCAND && j + 1 != y) { int p = atomicAdd(&S.cnt, 1); if (p < CAP) S.pool[p] = mkkey(X.y, j + 1); } \
        if (X.z > TCAND && j + 2 != y) { int p = atomicAdd(&S.cnt, 1); if (p < CAP) S.pool[p] = mkkey(X.z, j + 2); } \
        if (X.w > TCAND && j + 3 != y) { int p = atomicAdd(&S.cnt, 1); if (p < CAP) S.pool[p] = mkkey(X.w, j + 3); } \
      }                                                                                      \
    }
    PROC(x0, h0, q0) PROC(x1, h1, q1) PROC(x2, h2, q2) PROC(x3, h3, q3)
#undef PROC
  }
  for (int j = (C4 << 2) + tid; j < C; j += TPB) {  // scalar tail (C%4!=0 only)
    float z = zr[j];
    lmin = fminf(lmin, z);
    lsum += __expf(z);
    if (z > TCAND && j != y) { int p = atomicAdd(&S.cnt, 1); if (p < CAP) S.pool[p] = mkkey(z, j); }
  }

  lmin = wredMin(lmin);
  lsum = wredSum(lsum);
  if (lane == 0) { S.rmn[wid] = lmin; S.rsm[wid] = lsum; }
  __syncthreads();

  const int pc = S.cnt;                       // block-uniform
  float vmin = INFINITY, total = 0.0f;
#pragma unroll
  for (int w = 0; w < NW; ++w) { vmin = fminf(vmin, S.rmn[w]); total += S.rsm[w]; }
  const bool ok = (pc >= Keff && pc <= CAP);  // block-uniform

  // ---- Phase 2: top-Keff selection (value desc, index asc == jax stable) ----
  if (ok) {
    if (wid == 0) {  // barrier-free: wave 0, pool in registers, prev-bounded max
      u64 s0 = (lane < pc)       ? S.pool[lane]       : 0;
      u64 s1 = (lane + 64 < pc)  ? S.pool[lane + 64]  : 0;
      u64 s2 = (lane + 128 < pc) ? S.pool[lane + 128] : 0;
      u64 s3 = (lane + 192 < pc) ? S.pool[lane + 192] : 0;
      u64 sel[KTOP];
      u64 prev = ~0ull;
#pragma unroll
      for (int r = 0; r < KTOP; ++r) {
        u64 loc = 0;
        if (r < Keff) {
          if (s0 < prev && s0 > loc) loc = s0;
          if (s1 < prev && s1 > loc) loc = s1;
          if (s2 < prev && s2 > loc) loc = s2;
          if (s3 < prev && s3 > loc) loc = s3;
        }
        u64 best = wredMaxU64(loc);
        sel[r] = best;
        prev = best;
      }
      if (lane == 0) {
        float Stop = 0.0f;
#pragma unroll
        for (int r = 0; r < KTOP; ++r)
          if (sel[r] != 0) Stop += __expf(keyval(sel[r]));
        const float Sall = total - __expf(zy0);
        const float ev   = __expf(vmin);
        const float invZ = 1.0f / (Sall + ev);
        float Srest = Sall - Stop;
        if (Srest < 0.0f) Srest = 0.0f;
        float MR = (float)(C - 1 - Keff);
        if (MR < 1.0f) MR = 1.0f;
        S.c_prest = (Srest / MR) * invZ;
        S.c_ptrue = ev * invZ;
#pragma unroll
        for (int r = 0; r < KTOP; ++r) {
          bool have = (sel[r] != 0);
          S.pk[r] = have ? __expf(keyval(sel[r])) * invZ : 0.0f;
          S.ki[r] = have ? keyidx(sel[r]) : -1;
        }
      }
    }
  } else {
    // Guaranteed-exact fallback (pathological; ~never taken): block-wide
    // prev-bounded u64 max over the full row, Keff rounds.
    u64 prev = ~0ull;
    for (int r = 0; r < KTOP; ++r) {
      u64 loc = 0;
      if (r < Keff) {
        for (int j = tid; j < C; j += TPB) {
          if (j == y) continue;
          u64 k = mkkey(zr[j], j);
          if (k < prev && k > loc) loc = k;
        }
      }
      u64 best = wredMaxU64(loc);
      if (lane == 0) S.warr[wid] = best;
      __syncthreads();
      if (tid == 0) {
        u64 b = 0;
#pragma unroll
        for (int w = 0; w < NW; ++w) b = (S.warr[w] > b) ? S.warr[w] : b;
        S.selArr[r] = b;
      }
      __syncthreads();
      prev = S.selArr[r];
    }
    if (tid == 0) {
      float Stop = 0.0f;
#pragma unroll
      for (int r = 0; r < KTOP; ++r)
        if (S.selArr[r] != 0) Stop += __expf(keyval(S.selArr[r]));
      const float Sall = total - __expf(zy0);
      const float ev   = __expf(vmin);
      const float invZ = 1.0f / (Sall + ev);
      float Srest = Sall - Stop;
      if (Srest < 0.0f) Srest = 0.0f;
      float MR = (float)(C - 1 - Keff);
      if (MR < 1.0f) MR = 1.0f;
      S.c_prest = (Srest / MR) * invZ;
      S.c_ptrue = ev * invZ;
#pragma unroll
      for (int r = 0; r < KTOP; ++r) {
        bool have = (S.selArr[r] != 0);
        S.pk[r] = have ? __expf(keyval(S.selArr[r])) * invZ : 0.0f;
        S.ki[r] = have ? keyidx(S.selArr[r]) : -1;
      }
    }
  }
  __syncthreads();

  // ---- Phase 3: pure fill write. No input reads. ----
  const float p_rest = S.c_prest;
  const float p_true = S.c_ptrue;
  float pk[KTOP]; int ki[KTOP]; int sv[KTOP];
#pragma unroll
  for (int k = 0; k < KTOP; ++k) {
    pk[k] = S.pk[k];
    ki[k] = S.ki[k];
    sv[k] = ki[k] >> 2;    // -1 for absent -> group -1, never matches
  }
  const int svy = y >> 2;

  float* orow = out + (size_t)row * C;
  floatx4* out4 = (floatx4*)orow;
  const floatx4 fillv = {p_rest, p_rest, p_rest, p_rest};
  for (int base = 0; base < C4; base += 4 * TPB) {
#pragma unroll
    for (int u = 0; u < 4; ++u) {
      int g = base + tid + u * TPB;
      if (g < C4) {
        floatx4 o = fillv;
        bool sp = (g == svy);
#pragma unroll
        for (int k = 0; k < KTOP; ++k) sp |= (g == sv[k]);
        if (sp) {
          int j = g << 2;
#pragma unroll
          for (int l = 0; l < 4; ++l) {
            float p = p_rest;
#pragma unroll
            for (int k = 0; k < KTOP; ++k)
              if (j + l == ki[k]) p = pk[k];
            if (j + l == y) p = p_true;
            o[l] = p;
          }
        }
        __builtin_nontemporal_store(o, &out4[g]);
      }
    }
  }
  for (int j = (C4 << 2) + tid; j < C; j += TPB) {  // scalar tail
    float p = p_rest;
#pragma unroll
    for (int k = 0; k < KTOP; ++k)
      if (j == ki[k]) p = pk[k];
    if (j == y) p = p_true;
    __builtin_nontemporal_store(p, &orow[j]);
  }
}

extern "C" void kernel_launch(void* const* d_in, const int* in_sizes, int n_in,
                              void* d_out, int out_size, void* d_ws, size_t ws_size,
                              hipStream_t stream) {
  const float* zg = (const float*)d_in[0];
  const int* y    = (const int*)d_in[1];
  float* out      = (float*)d_out;
  const int B = in_sizes[1];
  const int C = in_sizes[0] / B;

  fused<<<B, TPB, 0, stream>>>(zg, y, out, B, C);
}